// Round 4
// baseline (586.196 us; speedup 1.0000x reference)
//
#include <hip/hip_runtime.h>
#include <hip/hip_bf16.h>
#include <hip/hip_cooperative_groups.h>

namespace cg = cooperative_groups;

#define NN 100000
#define NE 1600000
#define NGB 1563      // ceil(NN/64): blocks for MFMA GEMMs
#define MAXD 64       // padded neighbor slots per node; max in-degree (Poisson(16)) ~ 50
#define NPART 256     // edge parts
#define PCH 6250      // NE / NPART
#define NB2 391       // ceil(NN/256): buckets of 256 nodes
#define GPREP 1024    // cooperative grid (<= 2048 resident at launch_bounds(256,8))

typedef unsigned short ushort_t;
typedef __bf16 bf16x8 __attribute__((ext_vector_type(8)));
typedef float  f32x4  __attribute__((ext_vector_type(4)));

static __device__ __forceinline__ float bf2f(unsigned u) {     // low 16 bits -> f32
    union { unsigned i; float f; } c; c.i = u << 16; return c.f;
}
static __device__ __forceinline__ float bf2f_hi(unsigned u) {  // high 16 bits in place
    union { unsigned i; float f; } c; c.i = u & 0xffff0000u; return c.f;
}
static __device__ __forceinline__ ushort_t f2bf(float f) {
    union { __hip_bfloat16 b; ushort_t u; } c; c.b = __float2bfloat16(f); return c.u;
}

struct SM {
    int sA[512], sB[512];                          // scan scratch
    union {
        int hist[NB2];                             // phase 1
        struct { int bst[512]; int cur[NB2]; } p3; // phase 3
        struct { int bst[512]; int cur[256]; } p4; // phase 4
    } u;
};

// exclusive 512-slot scan of coltot -> bstOut (LDS), 256 threads, ping-pong
static __device__ void scan_bstart(SM& sm, const int* __restrict__ coltot,
                                   int* __restrict__ bstOut, int t) {
    int i0 = t, i1 = t + 256;
    int v0 = (i0 < NB2) ? coltot[i0] : 0;
    int v1 = (i1 < NB2) ? coltot[i1] : 0;
    sm.sA[i0] = v0; sm.sA[i1] = v1;
    __syncthreads();
    int* a = sm.sA; int* b = sm.sB;
    for (int o = 1; o < 512; o <<= 1) {
        b[i0] = a[i0] + (i0 >= o ? a[i0 - o] : 0);
        b[i1] = a[i1] + (i1 >= o ? a[i1 - o] : 0);
        __syncthreads();
        int* tmp = a; a = b; b = tmp;
    }
    bstOut[i0] = a[i0] - v0;   // exclusive prefix
    bstOut[i1] = a[i1] - v1;
    __syncthreads();
}

// ---- cooperative prep: hist -> colscan -> bucket scatter -> padded slot fill ----
__global__ __launch_bounds__(256, 8) void k_prep(
    const int* __restrict__ ei, const float* __restrict__ Wc, const float* __restrict__ Wl,
    int* __restrict__ bhist, int* __restrict__ basex, int* __restrict__ coltot,
    unsigned* __restrict__ ebuf, int* __restrict__ csrp,
    int* __restrict__ deg, float* __restrict__ dinv,
    ushort_t* __restrict__ wtb, ushort_t* __restrict__ w2tb)
{
    __shared__ SM sm;
    int t = threadIdx.x, bid = blockIdx.x, nb = gridDim.x;

    // ---- phase 1: per-part bucket histogram; last 32 blocks also do weight prep ----
    {
        int wc = bid - (nb - 32);
        if (wc >= 0) {
            int i = wc * 256 + t;              // 0..8191
            int d = i & 63, k = i >> 6;        // Wc[k][d], k<128
            wtb[d * 128 + k] = f2bf(Wc[i]);
            int j = i & 127, k2 = i >> 7;      // Wl[k2][j], k2<64
            w2tb[j * 64 + k2] = f2bf(Wl[i]);
        }
        const int* dst = ei + NE;
        for (int p = bid; p < NPART; p += nb) {
            for (int i = t; i < NB2; i += 256) sm.u.hist[i] = 0;
            __syncthreads();
            int e0 = p * PCH;
            for (int r = t; r < PCH; r += 256) atomicAdd(&sm.u.hist[dst[e0 + r] >> 8], 1);
            __syncthreads();
            for (int i = t; i < NB2; i += 256) bhist[p * NB2 + i] = sm.u.hist[i];
            __syncthreads();
        }
    }
    cg::this_grid().sync();

    // ---- phase 2: per-bucket exclusive scan across the 256 parts ----
    for (int k = bid; k < NB2; k += nb) {
        int v = bhist[t * NB2 + k];            // thread t = part t (NPART == 256)
        sm.sA[t] = v;
        __syncthreads();
        int* a = sm.sA; int* b = sm.sB;
        for (int o = 1; o < 256; o <<= 1) {
            b[t] = a[t] + (t >= o ? a[t - o] : 0);
            __syncthreads();
            int* tmp = a; a = b; b = tmp;
        }
        basex[t * NB2 + k] = a[t] - v;
        if (t == 255) coltot[k] = a[t];
        __syncthreads();
    }
    cg::this_grid().sync();

    // ---- phase 3: scatter edges into bucket-sorted ebuf (runs avg 16 x 4B = full sectors) ----
    scan_bstart(sm, coltot, sm.u.p3.bst, t);
    for (int p = bid; p < NPART; p += nb) {
        for (int i = t; i < NB2; i += 256) sm.u.p3.cur[i] = 0;
        __syncthreads();
        int e0 = p * PCH;
        for (int r = t; r < PCH; r += 256) {
            int e = e0 + r;
            int s = ei[e];
            int d = ei[NE + e];
            int k = d >> 8;
            int rk = atomicAdd(&sm.u.p3.cur[k], 1);   // LDS atomic
            int pos = sm.u.p3.bst[k] + basex[p * NB2 + k] + rk;
            ebuf[pos] = (unsigned)s | ((unsigned)(d & 255) << 17);
        }
        __syncthreads();
    }
    cg::this_grid().sync();

    // ---- phase 4: per-bucket slot fill (writes confined to 64KB L2-resident region) ----
    scan_bstart(sm, coltot, sm.u.p4.bst, t);
    for (int k = bid; k < NB2; k += nb) {
        int base = sm.u.p4.bst[k];
        int ne = coltot[k];
        sm.u.p4.cur[t] = 0;
        __syncthreads();
        for (int i = t; i < ne; i += 256) {
            unsigned pe = ebuf[base + i];
            int nl = pe >> 17;
            int rk = atomicAdd(&sm.u.p4.cur[nl], 1);  // LDS atomic
            if (rk < MAXD) csrp[(k * 256 + nl) * MAXD + rk] = (int)(pe & 0x1FFFF);
        }
        __syncthreads();
        int node = k * 256 + t;                       // < 100096, arrays sized for it
        int dgg = sm.u.p4.cur[t];
        deg[node]  = dgg;
        dinv[node] = rsqrtf((float)dgg + 1.0f);
        __syncthreads();
    }
}

// ---- MFMA GEMM 1 (LDS-free): hp[n][d] = bf16( dinv[n] * sum_k x[n][k] W[k][d] ) ----
__global__ __launch_bounds__(256) void k_gemm1(const float* __restrict__ x,
                                               const ushort_t* __restrict__ wtb,
                                               const float* __restrict__ dinv,
                                               ushort_t* __restrict__ hp) {
    int t = threadIdx.x;
    int w = t >> 6, lane = t & 63, l15 = lane & 15, quad = lane >> 4;
    int gn = blockIdx.x * 64 + w * 16 + l15;
    int gnc = gn < NN ? gn : NN - 1;
    const float*    xp = x   + (size_t)gnc * 128 + quad * 8;
    const ushort_t* wp = wtb + l15 * 128 + quad * 8;
    f32x4 acc[4];
#pragma unroll
    for (int dt = 0; dt < 4; ++dt) { acc[dt][0]=0.f; acc[dt][1]=0.f; acc[dt][2]=0.f; acc[dt][3]=0.f; }

#pragma unroll
    for (int kt = 0; kt < 4; ++kt) {
        float4 v0 = *(const float4*)(xp + kt * 32);
        float4 v1 = *(const float4*)(xp + kt * 32 + 4);
        union { ushort_t u[8]; bf16x8 v; } cv;
        cv.u[0]=f2bf(v0.x); cv.u[1]=f2bf(v0.y); cv.u[2]=f2bf(v0.z); cv.u[3]=f2bf(v0.w);
        cv.u[4]=f2bf(v1.x); cv.u[5]=f2bf(v1.y); cv.u[6]=f2bf(v1.z); cv.u[7]=f2bf(v1.w);
        bf16x8 bv = cv.v;
#pragma unroll
        for (int dt = 0; dt < 4; ++dt) {
            bf16x8 av = *(const bf16x8*)(wp + dt * 16 * 128 + kt * 32);
            acc[dt] = __builtin_amdgcn_mfma_f32_16x16x32_bf16(av, bv, acc[dt], 0, 0, 0);
        }
    }
    if (gn < NN) {
        float dv = dinv[gn];
#pragma unroll
        for (int dt = 0; dt < 4; ++dt) {
            // D row = quad*4+reg (d-local), col = l15 (node) -> 4 consecutive d per lane
            uint2 o;
            o.x = (unsigned)f2bf(dv * acc[dt][0]) | ((unsigned)f2bf(dv * acc[dt][1]) << 16);
            o.y = (unsigned)f2bf(dv * acc[dt][2]) | ((unsigned)f2bf(dv * acc[dt][3]) << 16);
            *(uint2*)&hp[(size_t)gn * 64 + dt * 16 + quad * 4] = o;
        }
    }
}

// ---- gather: 4 nodes/wave, 16-lane group per node; pad slots never dereferenced ----
__global__ __launch_bounds__(256) void k_gather(const int* __restrict__ deg,
                                                const float* __restrict__ dinv,
                                                const int* __restrict__ csrp,
                                                const ushort_t* __restrict__ hp,
                                                const float* __restrict__ b_conv,
                                                ushort_t* __restrict__ a) {
    int t = threadIdx.x;
    int lane = t & 63;
    int g = lane >> 4, l16 = lane & 15;
    int wave = (blockIdx.x * 256 + t) >> 6;     // 0..24999
    int node = wave * 4 + g;                    // group-uniform, < NN
    int cntt = deg[node];
    int cnt = cntt < MAXD ? cntt : MAXD;
    const ushort_t* hpc = hp + l16 * 4;

    // whole 64-slot neighbor row: 16 lanes x uint4
    uint4 colv = *(const uint4*)(csrp + node * MAXD + l16 * 4);

    // wave-uniform round count
    int cmax = cnt;
    { int o1 = __shfl_xor(cmax, 16, 64); cmax = cmax > o1 ? cmax : o1;
      int o2 = __shfl_xor(cmax, 32, 64); cmax = cmax > o2 ? cmax : o2; }

    float s0 = 0.f, s1 = 0.f, s2 = 0.f, s3 = 0.f;
#pragma unroll 1
    for (int j0 = 0; j0 < cmax; j0 += 8) {
        int base = (lane & 48) + (j0 >> 2);     // source lane for this group's slots
        int cc[8];
        cc[0] = __shfl((int)colv.x, base, 64);
        cc[1] = __shfl((int)colv.y, base, 64);
        cc[2] = __shfl((int)colv.z, base, 64);
        cc[3] = __shfl((int)colv.w, base, 64);
        cc[4] = __shfl((int)colv.x, base + 1, 64);
        cc[5] = __shfl((int)colv.y, base + 1, 64);
        cc[6] = __shfl((int)colv.z, base + 1, 64);
        cc[7] = __shfl((int)colv.w, base + 1, 64);
        int jrem = cnt - j0;                    // group-uniform remaining
        uint2 dd[8];
#pragma unroll
        for (int u = 0; u < 8; ++u) {
            int c = (u < jrem) ? cc[u] : node;  // dead slot -> own row (L1-hot)
            dd[u] = *(const uint2*)(hpc + (size_t)c * 64);
        }
#pragma unroll
        for (int u = 0; u < 8; ++u) {
            if (u >= jrem) { dd[u].x = 0u; dd[u].y = 0u; }
            s0 += bf2f(dd[u].x); s1 += bf2f_hi(dd[u].x);
            s2 += bf2f(dd[u].y); s3 += bf2f_hi(dd[u].y);
        }
    }
    // self-loop + bias + relu
    uint2 sl = *(const uint2*)(hpc + (size_t)node * 64);
    s0 += bf2f(sl.x); s1 += bf2f_hi(sl.x); s2 += bf2f(sl.y); s3 += bf2f_hi(sl.y);
    float dv = dinv[node];
    float4 bc = *(const float4*)(b_conv + l16 * 4);
    float v0 = fmaxf(dv * s0 + bc.x, 0.f);
    float v1 = fmaxf(dv * s1 + bc.y, 0.f);
    float v2 = fmaxf(dv * s2 + bc.z, 0.f);
    float v3 = fmaxf(dv * s3 + bc.w, 0.f);
    uint2 o;
    o.x = (unsigned)f2bf(v0) | ((unsigned)f2bf(v1) << 16);
    o.y = (unsigned)f2bf(v2) | ((unsigned)f2bf(v3) << 16);
    *(uint2*)&a[(size_t)node * 64 + l16 * 4] = o;
}

// ---- MFMA epilogue GEMM (LDS-free): out[n][j] = sum_k a[n][k] W2[k][j] + b_lin[j] ----
__global__ __launch_bounds__(256) void k_epi(const ushort_t* __restrict__ a,
                                             const ushort_t* __restrict__ w2tb,
                                             const float* __restrict__ blin,
                                             float* __restrict__ out) {
    int t = threadIdx.x;
    int w = t >> 6, lane = t & 63, l15 = lane & 15, quad = lane >> 4;
    int gn = blockIdx.x * 64 + w * 16 + l15;
    int gnc = gn < NN ? gn : NN - 1;
    const ushort_t* ap = a    + (size_t)gnc * 64 + quad * 8;
    const ushort_t* wp = w2tb + l15 * 64 + quad * 8;
    f32x4 acc[8];
#pragma unroll
    for (int jt = 0; jt < 8; ++jt) { acc[jt][0]=0.f; acc[jt][1]=0.f; acc[jt][2]=0.f; acc[jt][3]=0.f; }

#pragma unroll
    for (int kt = 0; kt < 2; ++kt) {
        bf16x8 bv = *(const bf16x8*)(ap + kt * 32);
#pragma unroll
        for (int jt = 0; jt < 8; ++jt) {
            bf16x8 av = *(const bf16x8*)(wp + jt * 16 * 64 + kt * 32);
            acc[jt] = __builtin_amdgcn_mfma_f32_16x16x32_bf16(av, bv, acc[jt], 0, 0, 0);
        }
    }
    if (gn < NN) {
#pragma unroll
        for (int jt = 0; jt < 8; ++jt) {
            int j0 = jt * 16 + quad * 4;
            float4 b4 = *(const float4*)(blin + j0);
            float4 o;
            o.x = acc[jt][0] + b4.x; o.y = acc[jt][1] + b4.y;
            o.z = acc[jt][2] + b4.z; o.w = acc[jt][3] + b4.w;
            *(float4*)&out[(size_t)gn * 128 + j0] = o;
        }
    }
}

extern "C" void kernel_launch(void* const* d_in, const int* in_sizes, int n_in,
                              void* d_out, int out_size, void* d_ws, size_t ws_size,
                              hipStream_t stream) {
    const float* x  = (const float*)d_in[0];
    const int*   ei = (const int*)d_in[1];
    const float* Wc = (const float*)d_in[2];
    const float* bc = (const float*)d_in[3];
    const float* Wl = (const float*)d_in[4];
    const float* bl = (const float*)d_in[5];
    float* out = (float*)d_out;

    char* ws = (char*)d_ws;
    // ~59.3 MB of 256 MiB; every consumed byte written first -> no memset needed
    int*      bhist  = (int*)(ws + 0);              // 256*391*4 = 400384
    int*      basex  = (int*)(ws + 400384);         // 400384
    int*      coltot = (int*)(ws + 800768);         // 2048 (391 used)
    int*      deg    = (int*)(ws + 802816);         // 100096*4 = 400384
    float*    dinv   = (float*)(ws + 1203200);      // 400384
    ushort_t* wtb    = (ushort_t*)(ws + 1603584);   // 16384
    ushort_t* w2tb   = (ushort_t*)(ws + 1619968);   // 16384
    unsigned* ebuf   = (unsigned*)(ws + 1636352);   // 6400000
    int*      csrp   = (int*)(ws + 8036352);        // 100096*64*4 = 25624576
    ushort_t* hp     = (ushort_t*)(ws + 33660928);  // 12800000 (bf16)
    ushort_t* a      = (ushort_t*)(ws + 46460928);  // 12800000 (bf16)

    void* args[12];
    args[0]  = (void*)&ei;   args[1]  = (void*)&Wc;   args[2]  = (void*)&Wl;
    args[3]  = (void*)&bhist; args[4] = (void*)&basex; args[5] = (void*)&coltot;
    args[6]  = (void*)&ebuf; args[7]  = (void*)&csrp; args[8]  = (void*)&deg;
    args[9]  = (void*)&dinv; args[10] = (void*)&wtb;  args[11] = (void*)&w2tb;
    hipLaunchCooperativeKernel((const void*)k_prep, dim3(GPREP), dim3(256), args, 0, stream);

    k_gemm1 <<<NGB, 256, 0, stream>>>(x, wtb, dinv, hp);
    k_gather<<<NN / 16, 256, 0, stream>>>(deg, dinv, csrp, hp, bc, a);
    k_epi   <<<NGB, 256, 0, stream>>>(a, w2tb, bl, out);
}

// Round 5
// 399.927 us; speedup vs baseline: 1.4658x; 1.4658x over previous
//
#include <hip/hip_runtime.h>
#include <hip/hip_bf16.h>

#define NN 100000
#define NE 1600000
#define NBUK 782      // ceil(NN/128): dst buckets of 128 nodes
#define NBLK 400      // edge partition blocks
#define CHUNK 4000    // edges per partition block (400*4000 = NE)
#define NGB 1563      // ceil(NN/64): blocks for MFMA GEMMs
#define MAXD 64       // padded neighbor slots per node; max in-degree (Poisson(16)) ~ 50

typedef unsigned short ushort_t;
typedef __bf16 bf16x8 __attribute__((ext_vector_type(8)));
typedef float  f32x4  __attribute__((ext_vector_type(4)));

static __device__ __forceinline__ float bf2f(unsigned u) {     // low 16 bits -> f32
    union { unsigned i; float f; } c; c.i = u << 16; return c.f;
}
static __device__ __forceinline__ float bf2f_hi(unsigned u) {  // high 16 bits in place
    union { unsigned i; float f; } c; c.i = u & 0xffff0000u; return c.f;
}
static __device__ __forceinline__ ushort_t f2bf(float f) {
    union { __hip_bfloat16 b; ushort_t u; } c; c.b = __float2bfloat16(f); return c.u;
}

// ---- launch 1: per-part bucket histogram (b<400) + weight prep (b>=400) + flag zero ----
__global__ __launch_bounds__(256) void k_pre(const int* __restrict__ ei,
                                             const float* __restrict__ Wc,
                                             const float* __restrict__ Wl,
                                             int* __restrict__ bhist,
                                             ushort_t* __restrict__ wtb,
                                             ushort_t* __restrict__ w2tb,
                                             int* __restrict__ dflag) {
    int b = blockIdx.x, t = threadIdx.x;
    if (b >= NBLK) {                       // weight prep: 32 blocks x 256 = 8192 threads
        int wc = b - NBLK;
        if (wc == 0 && t == 0) dflag[0] = 0;
        int i = wc * 256 + t;
        int d = i & 63, k = i >> 6;        // Wc[k][d], k<128
        wtb[d * 128 + k] = f2bf(Wc[i]);
        int j = i & 127, k2 = i >> 7;      // Wl[k2][j], k2<64
        w2tb[j * 64 + k2] = f2bf(Wl[i]);
        return;
    }
    __shared__ int h[NBUK];
    for (int i = t; i < NBUK; i += 256) h[i] = 0;
    __syncthreads();
    const int* dst = ei + NE;
    int e0 = b * CHUNK;
    for (int r = t; r < CHUNK; r += 256) atomicAdd(&h[dst[e0 + r] >> 7], 1);
    __syncthreads();
    for (int i = t; i < NBUK; i += 256) bhist[b * NBUK + i] = h[i];
}

// ---- launch 2: per-bucket scan across parts; last finishing block scans bucket totals ----
__global__ __launch_bounds__(512) void k_colscan(const int* __restrict__ bhist,
                                                 int* __restrict__ basex,
                                                 int* __restrict__ coltot,
                                                 int* __restrict__ bstart,
                                                 int* __restrict__ bcnt,
                                                 int* __restrict__ dflag) {
    __shared__ int s[512];
    __shared__ int sA[1024], sB[1024];
    __shared__ int isLast;
    int k = blockIdx.x, t = threadIdx.x;
    int v = (t < NBLK) ? bhist[t * NBUK + k] : 0;
    s[t] = v;
    __syncthreads();
#pragma unroll
    for (int o = 1; o < 512; o <<= 1) {
        int x = (t >= o) ? s[t - o] : 0;
        __syncthreads();
        s[t] += x;
        __syncthreads();
    }
    if (t < NBLK) basex[t * NBUK + k] = s[t] - v;
    if (t == 511) coltot[k] = s[511];
    __threadfence();
    __syncthreads();
    if (t == 0) isLast = (atomicAdd(dflag, 1) == NBUK - 1) ? 1 : 0;
    __syncthreads();
    if (!isLast) return;
    __threadfence();                        // acquire: all coltot writes visible
    // exclusive scan of coltot[782] -> bstart/bcnt (512 thr x 2 elems, ping-pong)
    int i0 = t, i1 = t + 512;
    int v0 = (i0 < NBUK) ? coltot[i0] : 0;
    int v1 = (i1 < NBUK) ? coltot[i1] : 0;
    sA[i0] = v0; sA[i1] = v1;
    __syncthreads();
    int* pa = sA; int* pb = sB;
#pragma unroll
    for (int o = 1; o < 1024; o <<= 1) {
        pb[i0] = pa[i0] + (i0 >= o ? pa[i0 - o] : 0);
        pb[i1] = pa[i1] + (i1 >= o ? pa[i1 - o] : 0);
        __syncthreads();
        int* tmp = pa; pa = pb; pb = tmp;
    }
    if (i0 < NBUK) { bstart[i0] = pa[i0] - v0; bcnt[i0] = v0; }
    if (i1 < NBUK) { bstart[i1] = pa[i1] - v1; bcnt[i1] = v1; }
}

// ---- launch 3: partition edges into bucket-sorted ebuf: src | (dst&127)<<17 ----
__global__ __launch_bounds__(256) void k_scatter2(const int* __restrict__ ei,
                                                  const int* __restrict__ bstart,
                                                  const int* __restrict__ basex,
                                                  unsigned* __restrict__ ebuf) {
    __shared__ int cur[NBUK];
    int t = threadIdx.x, b = blockIdx.x;
    for (int i = t; i < NBUK; i += 256) cur[i] = 0;
    __syncthreads();
    int e0 = b * CHUNK;
    for (int r = t; r < CHUNK; r += 256) {
        int e = e0 + r;
        int sv = ei[e];
        int dv = ei[NE + e];
        int k = dv >> 7;
        int rk = atomicAdd(&cur[k], 1);   // LDS int atomic
        int pos = bstart[k] + basex[b * NBUK + k] + rk;
        ebuf[pos] = (unsigned)sv | ((unsigned)(dv & 127) << 17);
    }
}

// ---- launch 4: per-bucket padded slot fill (32KB write window per block) + deg/dinv ----
__global__ __launch_bounds__(256) void k_sortp(const int* __restrict__ bstart,
                                               const int* __restrict__ bcnt,
                                               const unsigned* __restrict__ ebuf,
                                               int* __restrict__ csrp,
                                               int* __restrict__ deg,
                                               float* __restrict__ dinv) {
    __shared__ int cur[128];
    int t = threadIdx.x, b = blockIdx.x;
    if (t < 128) cur[t] = 0;
    __syncthreads();
    int base = bstart[b], ne = bcnt[b];
    for (int i = t; i < ne; i += 256) {
        unsigned pe = ebuf[base + i];
        int nl = pe >> 17;
        int rk = atomicAdd(&cur[nl], 1);  // LDS int atomic
        if (rk < MAXD) csrp[(b * 128 + nl) * MAXD + rk] = (int)(pe & 0x1FFFF);
    }
    __syncthreads();
    if (t < 128) {
        int node = b * 128 + t;           // arrays sized for 100096
        int dg = cur[t];
        deg[node]  = dg;
        dinv[node] = rsqrtf((float)dg + 1.0f);
    }
}

// ---- launch 5: MFMA GEMM 1 (LDS-free): hp[n][d] = bf16( dinv[n] * (x W)[n][d] ) ----
__global__ __launch_bounds__(256) void k_gemm1(const float* __restrict__ x,
                                               const ushort_t* __restrict__ wtb,
                                               const float* __restrict__ dinv,
                                               ushort_t* __restrict__ hp) {
    int t = threadIdx.x;
    int w = t >> 6, lane = t & 63, l15 = lane & 15, quad = lane >> 4;
    int gn = blockIdx.x * 64 + w * 16 + l15;
    int gnc = gn < NN ? gn : NN - 1;
    const float*    xp = x   + (size_t)gnc * 128 + quad * 8;
    const ushort_t* wp = wtb + l15 * 128 + quad * 8;
    f32x4 acc[4];
#pragma unroll
    for (int dt = 0; dt < 4; ++dt) { acc[dt][0]=0.f; acc[dt][1]=0.f; acc[dt][2]=0.f; acc[dt][3]=0.f; }

#pragma unroll
    for (int kt = 0; kt < 4; ++kt) {
        float4 v0 = *(const float4*)(xp + kt * 32);
        float4 v1 = *(const float4*)(xp + kt * 32 + 4);
        union { ushort_t u[8]; bf16x8 v; } cv;
        cv.u[0]=f2bf(v0.x); cv.u[1]=f2bf(v0.y); cv.u[2]=f2bf(v0.z); cv.u[3]=f2bf(v0.w);
        cv.u[4]=f2bf(v1.x); cv.u[5]=f2bf(v1.y); cv.u[6]=f2bf(v1.z); cv.u[7]=f2bf(v1.w);
        bf16x8 bv = cv.v;
#pragma unroll
        for (int dt = 0; dt < 4; ++dt) {
            bf16x8 av = *(const bf16x8*)(wp + dt * 16 * 128 + kt * 32);
            acc[dt] = __builtin_amdgcn_mfma_f32_16x16x32_bf16(av, bv, acc[dt], 0, 0, 0);
        }
    }
    if (gn < NN) {
        float dv = dinv[gn];
#pragma unroll
        for (int dt = 0; dt < 4; ++dt) {
            // D row = quad*4+reg (d-local), col = l15 (node) -> 4 consecutive d per lane
            uint2 o;
            o.x = (unsigned)f2bf(dv * acc[dt][0]) | ((unsigned)f2bf(dv * acc[dt][1]) << 16);
            o.y = (unsigned)f2bf(dv * acc[dt][2]) | ((unsigned)f2bf(dv * acc[dt][3]) << 16);
            *(uint2*)&hp[(size_t)gn * 64 + dt * 16 + quad * 4] = o;
        }
    }
}

// ---- launch 6: fused gather + epilogue GEMM ----
// Phase A: 4 iterations x (4 nodes/wave, 16-lane group per node) -> a-tile in LDS (64x72 bf16).
// Phase B: per wave, 16 nodes x 128 cols MFMA vs W2^T; out = acc + b_lin.
__global__ __launch_bounds__(256) void k_gafin(const int* __restrict__ deg,
                                               const float* __restrict__ dinv,
                                               const int* __restrict__ csrp,
                                               const ushort_t* __restrict__ hp,
                                               const float* __restrict__ b_conv,
                                               const ushort_t* __restrict__ w2tb,
                                               const float* __restrict__ blin,
                                               float* __restrict__ out) {
    __shared__ __align__(16) ushort_t as[64 * 72];   // a-tile, +8 pad (2-way banks only)
    int t = threadIdx.x;
    int w = t >> 6, lane = t & 63;
    int g = lane >> 4, l16 = lane & 15;
    int node0 = blockIdx.x * 64;

    float4 bc = *(const float4*)(b_conv + l16 * 4);

#pragma unroll 1
    for (int it = 0; it < 4; ++it) {
        int nl = it * 16 + w * 4 + g;               // 0..63, group-uniform
        int node = node0 + nl;                       // < 100032 (< 100096 array bound)
        int nodeR = node < NN ? node : NN - 1;       // clamp for hp reads
        int cntt = deg[node];                        // 0 for fake nodes
        int cnt = cntt < MAXD ? cntt : MAXD;
        const ushort_t* hpc = hp + l16 * 4;

        uint4 colv = *(const uint4*)(csrp + node * MAXD + l16 * 4);

        int cmax = cnt;
        { int o1 = __shfl_xor(cmax, 16, 64); cmax = cmax > o1 ? cmax : o1;
          int o2 = __shfl_xor(cmax, 32, 64); cmax = cmax > o2 ? cmax : o2; }

        float s0 = 0.f, s1 = 0.f, s2 = 0.f, s3 = 0.f;
#pragma unroll 1
        for (int j0 = 0; j0 < cmax; j0 += 8) {
            int base = (lane & 48) + (j0 >> 2);     // source lane within group
            int cc[8];
            cc[0] = __shfl((int)colv.x, base, 64);
            cc[1] = __shfl((int)colv.y, base, 64);
            cc[2] = __shfl((int)colv.z, base, 64);
            cc[3] = __shfl((int)colv.w, base, 64);
            cc[4] = __shfl((int)colv.x, base + 1, 64);
            cc[5] = __shfl((int)colv.y, base + 1, 64);
            cc[6] = __shfl((int)colv.z, base + 1, 64);
            cc[7] = __shfl((int)colv.w, base + 1, 64);
            int jrem = cnt - j0;                    // group-uniform remaining
            uint2 dd[8];
#pragma unroll
            for (int u = 0; u < 8; ++u) {
                int c = (u < jrem) ? cc[u] : nodeR; // dead slot -> own row (L1-hot)
                dd[u] = *(const uint2*)(hpc + (size_t)c * 64);
            }
#pragma unroll
            for (int u = 0; u < 8; ++u) {
                if (u >= jrem) { dd[u].x = 0u; dd[u].y = 0u; }
                s0 += bf2f(dd[u].x); s1 += bf2f_hi(dd[u].x);
                s2 += bf2f(dd[u].y); s3 += bf2f_hi(dd[u].y);
            }
        }
        // self-loop + bias + relu
        uint2 sl = *(const uint2*)(hpc + (size_t)nodeR * 64);
        s0 += bf2f(sl.x); s1 += bf2f_hi(sl.x); s2 += bf2f(sl.y); s3 += bf2f_hi(sl.y);
        float dv = dinv[node];
        float v0 = fmaxf(dv * s0 + bc.x, 0.f);
        float v1 = fmaxf(dv * s1 + bc.y, 0.f);
        float v2 = fmaxf(dv * s2 + bc.z, 0.f);
        float v3 = fmaxf(dv * s3 + bc.w, 0.f);
        uint2 o;
        o.x = (unsigned)f2bf(v0) | ((unsigned)f2bf(v1) << 16);
        o.y = (unsigned)f2bf(v2) | ((unsigned)f2bf(v3) << 16);
        *(uint2*)&as[nl * 72 + l16 * 4] = o;
    }
    __syncthreads();

    // ---- Phase B: epilogue MFMA from LDS a-tile ----
    int l15 = lane & 15, quad = lane >> 4;
    int gn = node0 + w * 16 + l15;
    const ushort_t* ap = &as[(w * 16 + l15) * 72 + quad * 8];
    const ushort_t* wp = w2tb + l15 * 64 + quad * 8;
    f32x4 acc[8];
#pragma unroll
    for (int jt = 0; jt < 8; ++jt) { acc[jt][0]=0.f; acc[jt][1]=0.f; acc[jt][2]=0.f; acc[jt][3]=0.f; }

#pragma unroll
    for (int kt = 0; kt < 2; ++kt) {
        bf16x8 bv = *(const bf16x8*)(ap + kt * 32);
#pragma unroll
        for (int jt = 0; jt < 8; ++jt) {
            bf16x8 av = *(const bf16x8*)(wp + jt * 16 * 64 + kt * 32);
            acc[jt] = __builtin_amdgcn_mfma_f32_16x16x32_bf16(av, bv, acc[jt], 0, 0, 0);
        }
    }
    if (gn < NN) {
#pragma unroll
        for (int jt = 0; jt < 8; ++jt) {
            int j0 = jt * 16 + quad * 4;
            float4 b4 = *(const float4*)(blin + j0);
            float4 o;
            o.x = acc[jt][0] + b4.x; o.y = acc[jt][1] + b4.y;
            o.z = acc[jt][2] + b4.z; o.w = acc[jt][3] + b4.w;
            *(float4*)&out[(size_t)gn * 128 + j0] = o;
        }
    }
}

extern "C" void kernel_launch(void* const* d_in, const int* in_sizes, int n_in,
                              void* d_out, int out_size, void* d_ws, size_t ws_size,
                              hipStream_t stream) {
    const float* x  = (const float*)d_in[0];
    const int*   ei = (const int*)d_in[1];
    const float* Wc = (const float*)d_in[2];
    const float* bc = (const float*)d_in[3];
    const float* Wl = (const float*)d_in[4];
    const float* bl = (const float*)d_in[5];
    float* out = (float*)d_out;

    char* ws = (char*)d_ws;
    // ~48.2 MB of 256 MiB; every consumed byte written before read -> no memset needed
    int*      bhist  = (int*)(ws + 0);              // 400*782*4 = 1251200
    int*      basex  = (int*)(ws + 1251200);        // 1251200
    int*      coltot = (int*)(ws + 2502400);        // 3200
    int*      bstart = (int*)(ws + 2505600);        // 3200
    int*      bcnt   = (int*)(ws + 2508800);        // 3200
    int*      dflag  = (int*)(ws + 2512000);        // 64
    int*      deg    = (int*)(ws + 2512064);        // 100096*4 = 400384
    float*    dinv   = (float*)(ws + 2912448);      // 400384
    ushort_t* wtb    = (ushort_t*)(ws + 3312832);   // 16384
    ushort_t* w2tb   = (ushort_t*)(ws + 3329216);   // 16384
    unsigned* ebuf   = (unsigned*)(ws + 3345600);   // 6400000
    int*      csrp   = (int*)(ws + 9745600);        // 100096*64*4 = 25624576
    ushort_t* hp     = (ushort_t*)(ws + 35370176);  // 12800000 (bf16)

    k_pre     <<<NBLK + 32, 256, 0, stream>>>(ei, Wc, Wl, bhist, wtb, w2tb, dflag);
    k_colscan <<<NBUK, 512, 0, stream>>>(bhist, basex, coltot, bstart, bcnt, dflag);
    k_scatter2<<<NBLK, 256, 0, stream>>>(ei, bstart, basex, ebuf);
    k_sortp   <<<NBUK, 256, 0, stream>>>(bstart, bcnt, ebuf, csrp, deg, dinv);
    k_gemm1   <<<NGB, 256, 0, stream>>>(x, wtb, dinv, hp);
    k_gafin   <<<NGB, 256, 0, stream>>>(deg, dinv, csrp, hp, bc, w2tb, bl, out);
}

// Round 6
// 231.936 us; speedup vs baseline: 2.5274x; 1.7243x over previous
//
#include <hip/hip_runtime.h>
#include <hip/hip_bf16.h>

#define NN 100000
#define NE 1600000
#define NBUK 782      // ceil(NN/128): dst buckets of 128 nodes
#define NBLK 400      // edge partition blocks
#define CHUNK 4000    // edges per partition block (400*4000 = NE)
#define NGB 1563      // ceil(NN/64): blocks for MFMA GEMMs
#define MAXD 64       // padded neighbor slots per node; max in-degree (Poisson(16)) ~ 50

typedef unsigned short ushort_t;
typedef __bf16 bf16x8 __attribute__((ext_vector_type(8)));
typedef float  f32x4  __attribute__((ext_vector_type(4)));

static __device__ __forceinline__ float bf2f(unsigned u) {     // low 16 bits -> f32
    union { unsigned i; float f; } c; c.i = u << 16; return c.f;
}
static __device__ __forceinline__ float bf2f_hi(unsigned u) {  // high 16 bits in place
    union { unsigned i; float f; } c; c.i = u & 0xffff0000u; return c.f;
}
static __device__ __forceinline__ ushort_t f2bf(float f) {
    union { __hip_bfloat16 b; ushort_t u; } c; c.b = __float2bfloat16(f); return c.u;
}

// ---- launch 1: per-part bucket histogram (b<400) + weight prep (b>=400) ----
__global__ __launch_bounds__(256) void k_pre(const int* __restrict__ ei,
                                             const float* __restrict__ Wc,
                                             const float* __restrict__ Wl,
                                             int* __restrict__ bhist,
                                             ushort_t* __restrict__ wtb,
                                             ushort_t* __restrict__ w2tb) {
    int b = blockIdx.x, t = threadIdx.x;
    if (b >= NBLK) {                       // weight prep: 32 blocks x 256 = 8192 threads
        int i = (b - NBLK) * 256 + t;
        int d = i & 63, k = i >> 6;        // Wc[k][d], k<128
        wtb[d * 128 + k] = f2bf(Wc[i]);
        int j = i & 127, k2 = i >> 7;      // Wl[k2][j], k2<64
        w2tb[j * 64 + k2] = f2bf(Wl[i]);
        return;
    }
    __shared__ int h[NBUK];
    for (int i = t; i < NBUK; i += 256) h[i] = 0;
    __syncthreads();
    const int* dst = ei + NE;
    int e0 = b * CHUNK;
    for (int r = t; r < CHUNK; r += 256) atomicAdd(&h[dst[e0 + r] >> 7], 1);
    __syncthreads();
    for (int i = t; i < NBUK; i += 256) bhist[b * NBUK + i] = h[i];
}

// ---- launch 2: per-bucket exclusive scan across parts -> basex, coltot (NO fences) ----
__global__ __launch_bounds__(512) void k_colscan(const int* __restrict__ bhist,
                                                 int* __restrict__ basex,
                                                 int* __restrict__ coltot) {
    __shared__ int s[512];
    int k = blockIdx.x, t = threadIdx.x;
    int v = (t < NBLK) ? bhist[t * NBUK + k] : 0;
    s[t] = v;
    __syncthreads();
#pragma unroll
    for (int o = 1; o < 512; o <<= 1) {
        int x = (t >= o) ? s[t - o] : 0;
        __syncthreads();
        s[t] += x;
        __syncthreads();
    }
    if (t < NBLK) basex[t * NBUK + k] = s[t] - v;
    if (t == 511) coltot[k] = s[511];
}

// ---- launch 3: partition edges into bucket-sorted ebuf: src | (dst&127)<<17 ----
// Rebuilds the bucket-base exclusive scan locally (coltot is 3KB, L2-hot).
__global__ __launch_bounds__(256) void k_scatter2(const int* __restrict__ ei,
                                                  const int* __restrict__ coltot,
                                                  const int* __restrict__ basex,
                                                  unsigned* __restrict__ ebuf) {
    __shared__ int cur[NBUK];
    __shared__ int bst[NBUK];
    __shared__ int ssum[256];
    int t = threadIdx.x, b = blockIdx.x;
    // local exclusive scan of coltot[0..NBUK): 4 elems/thread + 256-wide Hillis-Steele
    int v0 = 0, v1 = 0, v2 = 0, v3 = 0;
    int i4 = t * 4;
    if (i4 + 0 < NBUK) v0 = coltot[i4 + 0];
    if (i4 + 1 < NBUK) v1 = coltot[i4 + 1];
    if (i4 + 2 < NBUK) v2 = coltot[i4 + 2];
    if (i4 + 3 < NBUK) v3 = coltot[i4 + 3];
    int tot = v0 + v1 + v2 + v3;
    ssum[t] = tot;
    for (int i = t; i < NBUK; i += 256) cur[i] = 0;
    __syncthreads();
#pragma unroll
    for (int o = 1; o < 256; o <<= 1) {
        int x = (t >= o) ? ssum[t - o] : 0;
        __syncthreads();
        ssum[t] += x;
        __syncthreads();
    }
    int run = ssum[t] - tot;
    if (i4 + 0 < NBUK) { bst[i4 + 0] = run; run += v0; }
    if (i4 + 1 < NBUK) { bst[i4 + 1] = run; run += v1; }
    if (i4 + 2 < NBUK) { bst[i4 + 2] = run; run += v2; }
    if (i4 + 3 < NBUK) { bst[i4 + 3] = run; run += v3; }
    __syncthreads();

    int e0 = b * CHUNK;
    for (int r = t; r < CHUNK; r += 256) {
        int e = e0 + r;
        int sv = ei[e];
        int dv = ei[NE + e];
        int k = dv >> 7;
        int rk = atomicAdd(&cur[k], 1);   // LDS int atomic
        int pos = bst[k] + basex[b * NBUK + k] + rk;
        ebuf[pos] = (unsigned)sv | ((unsigned)(dv & 127) << 17);
    }
}

// ---- launch 4: per-bucket padded slot fill (32KB write window per block) + deg/dinv ----
// Needs only this bucket's base = sum(coltot[0..b-1]): strided reduce, no global scan.
__global__ __launch_bounds__(256) void k_sortp(const int* __restrict__ coltot,
                                               const unsigned* __restrict__ ebuf,
                                               int* __restrict__ csrp,
                                               int* __restrict__ deg,
                                               float* __restrict__ dinv) {
    __shared__ int cur[128];
    __shared__ int ssum[256];
    int t = threadIdx.x, b = blockIdx.x;
    int s = 0;
    for (int i = t; i < b; i += 256) s += coltot[i];
    ssum[t] = s;
    if (t < 128) cur[t] = 0;
    __syncthreads();
#pragma unroll
    for (int o = 128; o > 0; o >>= 1) {
        if (t < o) ssum[t] += ssum[t + o];
        __syncthreads();
    }
    int base = ssum[0];
    int ne = coltot[b];
    for (int i = t; i < ne; i += 256) {
        unsigned pe = ebuf[base + i];
        int nl = pe >> 17;
        int rk = atomicAdd(&cur[nl], 1);  // LDS int atomic
        if (rk < MAXD) csrp[(b * 128 + nl) * MAXD + rk] = (int)(pe & 0x1FFFF);
    }
    __syncthreads();
    if (t < 128) {
        int node = b * 128 + t;           // arrays sized for 100096
        int dg = cur[t];
        deg[node]  = dg;
        dinv[node] = rsqrtf((float)dg + 1.0f);
    }
}

// ---- launch 5: MFMA GEMM 1 (LDS-free): hp[n][d] = bf16( dinv[n] * (x W)[n][d] ) ----
__global__ __launch_bounds__(256) void k_gemm1(const float* __restrict__ x,
                                               const ushort_t* __restrict__ wtb,
                                               const float* __restrict__ dinv,
                                               ushort_t* __restrict__ hp) {
    int t = threadIdx.x;
    int w = t >> 6, lane = t & 63, l15 = lane & 15, quad = lane >> 4;
    int gn = blockIdx.x * 64 + w * 16 + l15;
    int gnc = gn < NN ? gn : NN - 1;
    const float*    xp = x   + (size_t)gnc * 128 + quad * 8;
    const ushort_t* wp = wtb + l15 * 128 + quad * 8;
    f32x4 acc[4];
#pragma unroll
    for (int dt = 0; dt < 4; ++dt) { acc[dt][0]=0.f; acc[dt][1]=0.f; acc[dt][2]=0.f; acc[dt][3]=0.f; }

#pragma unroll
    for (int kt = 0; kt < 4; ++kt) {
        float4 v0 = *(const float4*)(xp + kt * 32);
        float4 v1 = *(const float4*)(xp + kt * 32 + 4);
        union { ushort_t u[8]; bf16x8 v; } cv;
        cv.u[0]=f2bf(v0.x); cv.u[1]=f2bf(v0.y); cv.u[2]=f2bf(v0.z); cv.u[3]=f2bf(v0.w);
        cv.u[4]=f2bf(v1.x); cv.u[5]=f2bf(v1.y); cv.u[6]=f2bf(v1.z); cv.u[7]=f2bf(v1.w);
        bf16x8 bv = cv.v;
#pragma unroll
        for (int dt = 0; dt < 4; ++dt) {
            bf16x8 av = *(const bf16x8*)(wp + dt * 16 * 128 + kt * 32);
            acc[dt] = __builtin_amdgcn_mfma_f32_16x16x32_bf16(av, bv, acc[dt], 0, 0, 0);
        }
    }
    if (gn < NN) {
        float dv = dinv[gn];
#pragma unroll
        for (int dt = 0; dt < 4; ++dt) {
            // D row = quad*4+reg (d-local), col = l15 (node) -> 4 consecutive d per lane
            uint2 o;
            o.x = (unsigned)f2bf(dv * acc[dt][0]) | ((unsigned)f2bf(dv * acc[dt][1]) << 16);
            o.y = (unsigned)f2bf(dv * acc[dt][2]) | ((unsigned)f2bf(dv * acc[dt][3]) << 16);
            *(uint2*)&hp[(size_t)gn * 64 + dt * 16 + quad * 4] = o;
        }
    }
}

// ---- launch 6: fused gather + epilogue GEMM ----
// Phase A: 4 iterations x (4 nodes/wave, 16-lane group per node) -> a-tile in LDS (64x72 bf16).
// Phase B: per wave, 16 nodes x 128 cols MFMA vs W2^T; out = acc + b_lin.
__global__ __launch_bounds__(256) void k_gafin(const int* __restrict__ deg,
                                               const float* __restrict__ dinv,
                                               const int* __restrict__ csrp,
                                               const ushort_t* __restrict__ hp,
                                               const float* __restrict__ b_conv,
                                               const ushort_t* __restrict__ w2tb,
                                               const float* __restrict__ blin,
                                               float* __restrict__ out) {
    __shared__ __align__(16) ushort_t as[64 * 72];   // a-tile, +8 pad (2-way banks only)
    int t = threadIdx.x;
    int w = t >> 6, lane = t & 63;
    int g = lane >> 4, l16 = lane & 15;
    int node0 = blockIdx.x * 64;

    float4 bc = *(const float4*)(b_conv + l16 * 4);

#pragma unroll 1
    for (int it = 0; it < 4; ++it) {
        int nl = it * 16 + w * 4 + g;               // 0..63, group-uniform
        int node = node0 + nl;                       // < 100032 (< 100096 array bound)
        int nodeR = node < NN ? node : NN - 1;       // clamp for hp reads
        int cntt = deg[node];                        // 0 for fake nodes
        int cnt = cntt < MAXD ? cntt : MAXD;
        const ushort_t* hpc = hp + l16 * 4;

        uint4 colv = *(const uint4*)(csrp + node * MAXD + l16 * 4);

        int cmax = cnt;
        { int o1 = __shfl_xor(cmax, 16, 64); cmax = cmax > o1 ? cmax : o1;
          int o2 = __shfl_xor(cmax, 32, 64); cmax = cmax > o2 ? cmax : o2; }

        float s0 = 0.f, s1 = 0.f, s2 = 0.f, s3 = 0.f;
#pragma unroll 1
        for (int j0 = 0; j0 < cmax; j0 += 8) {
            int base = (lane & 48) + (j0 >> 2);     // source lane within group
            int cc[8];
            cc[0] = __shfl((int)colv.x, base, 64);
            cc[1] = __shfl((int)colv.y, base, 64);
            cc[2] = __shfl((int)colv.z, base, 64);
            cc[3] = __shfl((int)colv.w, base, 64);
            cc[4] = __shfl((int)colv.x, base + 1, 64);
            cc[5] = __shfl((int)colv.y, base + 1, 64);
            cc[6] = __shfl((int)colv.z, base + 1, 64);
            cc[7] = __shfl((int)colv.w, base + 1, 64);
            int jrem = cnt - j0;                    // group-uniform remaining
            uint2 dd[8];
#pragma unroll
            for (int u = 0; u < 8; ++u) {
                int c = (u < jrem) ? cc[u] : nodeR; // dead slot -> own row (L1-hot)
                dd[u] = *(const uint2*)(hpc + (size_t)c * 64);
            }
#pragma unroll
            for (int u = 0; u < 8; ++u) {
                if (u >= jrem) { dd[u].x = 0u; dd[u].y = 0u; }
                s0 += bf2f(dd[u].x); s1 += bf2f_hi(dd[u].x);
                s2 += bf2f(dd[u].y); s3 += bf2f_hi(dd[u].y);
            }
        }
        // self-loop + bias + relu
        uint2 sl = *(const uint2*)(hpc + (size_t)nodeR * 64);
        s0 += bf2f(sl.x); s1 += bf2f_hi(sl.x); s2 += bf2f(sl.y); s3 += bf2f_hi(sl.y);
        float dv = dinv[node];
        float v0 = fmaxf(dv * s0 + bc.x, 0.f);
        float v1 = fmaxf(dv * s1 + bc.y, 0.f);
        float v2 = fmaxf(dv * s2 + bc.z, 0.f);
        float v3 = fmaxf(dv * s3 + bc.w, 0.f);
        uint2 o;
        o.x = (unsigned)f2bf(v0) | ((unsigned)f2bf(v1) << 16);
        o.y = (unsigned)f2bf(v2) | ((unsigned)f2bf(v3) << 16);
        *(uint2*)&as[nl * 72 + l16 * 4] = o;
    }
    __syncthreads();

    // ---- Phase B: epilogue MFMA from LDS a-tile ----
    int l15 = lane & 15, quad = lane >> 4;
    int gn = node0 + w * 16 + l15;
    const ushort_t* ap = &as[(w * 16 + l15) * 72 + quad * 8];
    const ushort_t* wp = w2tb + l15 * 64 + quad * 8;
    f32x4 acc[8];
#pragma unroll
    for (int jt = 0; jt < 8; ++jt) { acc[jt][0]=0.f; acc[jt][1]=0.f; acc[jt][2]=0.f; acc[jt][3]=0.f; }

#pragma unroll
    for (int kt = 0; kt < 2; ++kt) {
        bf16x8 bv = *(const bf16x8*)(ap + kt * 32);
#pragma unroll
        for (int jt = 0; jt < 8; ++jt) {
            bf16x8 av = *(const bf16x8*)(wp + jt * 16 * 64 + kt * 32);
            acc[jt] = __builtin_amdgcn_mfma_f32_16x16x32_bf16(av, bv, acc[jt], 0, 0, 0);
        }
    }
    if (gn < NN) {
#pragma unroll
        for (int jt = 0; jt < 8; ++jt) {
            int j0 = jt * 16 + quad * 4;
            float4 b4 = *(const float4*)(blin + j0);
            float4 o;
            o.x = acc[jt][0] + b4.x; o.y = acc[jt][1] + b4.y;
            o.z = acc[jt][2] + b4.z; o.w = acc[jt][3] + b4.w;
            *(float4*)&out[(size_t)gn * 128 + j0] = o;
        }
    }
}

extern "C" void kernel_launch(void* const* d_in, const int* in_sizes, int n_in,
                              void* d_out, int out_size, void* d_ws, size_t ws_size,
                              hipStream_t stream) {
    const float* x  = (const float*)d_in[0];
    const int*   ei = (const int*)d_in[1];
    const float* Wc = (const float*)d_in[2];
    const float* bc = (const float*)d_in[3];
    const float* Wl = (const float*)d_in[4];
    const float* bl = (const float*)d_in[5];
    float* out = (float*)d_out;

    char* ws = (char*)d_ws;
    // ~48.2 MB of 256 MiB; every consumed byte written before read -> no memset needed
    int*      bhist  = (int*)(ws + 0);              // 400*782*4 = 1251200
    int*      basex  = (int*)(ws + 1251200);        // 1251200
    int*      coltot = (int*)(ws + 2502400);        // 3200
    int*      deg    = (int*)(ws + 2512064);        // 100096*4 = 400384
    float*    dinv   = (float*)(ws + 2912448);      // 400384
    ushort_t* wtb    = (ushort_t*)(ws + 3312832);   // 16384
    ushort_t* w2tb   = (ushort_t*)(ws + 3329216);   // 16384
    unsigned* ebuf   = (unsigned*)(ws + 3345600);   // 6400000
    int*      csrp   = (int*)(ws + 9745600);        // 100096*64*4 = 25624576
    ushort_t* hp     = (ushort_t*)(ws + 35370176);  // 12800000 (bf16)

    k_pre     <<<NBLK + 32, 256, 0, stream>>>(ei, Wc, Wl, bhist, wtb, w2tb);
    k_colscan <<<NBUK, 512, 0, stream>>>(bhist, basex, coltot);
    k_scatter2<<<NBLK, 256, 0, stream>>>(ei, coltot, basex, ebuf);
    k_sortp   <<<NBUK, 256, 0, stream>>>(coltot, ebuf, csrp, deg, dinv);
    k_gemm1   <<<NGB, 256, 0, stream>>>(x, wtb, dinv, hp);
    k_gafin   <<<NGB, 256, 0, stream>>>(deg, dinv, csrp, hp, bc, w2tb, bl, out);
}